// Round 1
// baseline (59.515 us; speedup 1.0000x reference)
//
#include <hip/hip_runtime.h>

// Persistence image: out[b,d,i,j] = sum_p w_p * exp(-50*((x_i-birth_p)^2 + (y_j-pers_p)^2))
// with w_p = max(pers_p, 0), pers_p = death_p - birth_p, x_i = i/19, y_j = j/19.
// Separable Gaussian: per point build gxw[i] = w*exp(-50*(x_i-b)^2) and
// gy[j] = exp(-50*(y_j-p)^2) in LDS, then cells accumulate gxw[i]*gy[j].

#define RX 20
#define RY 20
#define SPLIT 8        // blocks per (b,d); 96*8 = 768 blocks -> ~3 blocks/CU
#define CHUNK 256      // points per block (one per thread in phase 1)
#define STRIDE 22      // padded LDS row stride in floats: 88B = 8B-aligned, gcd(22,32)=2

__global__ __launch_bounds__(256) void pimg_kernel(const float2* __restrict__ pd,
                                                   float* __restrict__ out,
                                                   int n_bd) {
    __shared__ __attribute__((aligned(16))) float s_gxw[CHUNK * STRIDE];
    __shared__ __attribute__((aligned(16))) float s_gy[CHUNK * STRIDE];
    __shared__ int s_wave_cnt[4];

    const int tid   = threadIdx.x;
    const int bd    = blockIdx.x / SPLIT;
    const int chunk = blockIdx.x % SPLIT;
    const int pbase = bd * 2048 + chunk * CHUNK;

    // ---- Phase 1: load one point per thread, compact active (pers>0) into LDS tables
    float2 p2  = pd[pbase + tid];        // (birth, death), coalesced 8B/lane
    float birth = p2.x;
    float pers  = p2.y - p2.x;
    bool active = pers > 0.0f;

    unsigned long long mask = __ballot(active);
    int lane = tid & 63;
    int wid  = tid >> 6;
    int rank = __popcll(mask & ((1ull << lane) - 1ull));
    if (lane == 0) s_wave_cnt[wid] = __popcll(mask);
    __syncthreads();

    int offset = 0;
    #pragma unroll
    for (int w = 0; w < 4; ++w)
        if (w < wid) offset += s_wave_cnt[w];
    int total = s_wave_cnt[0] + s_wave_cnt[1] + s_wave_cnt[2] + s_wave_cnt[3];

    if (active) {
        int slot = offset + rank;
        #pragma unroll
        for (int i = 0; i < RX; ++i) {
            float xi = i * (1.0f / 19.0f);
            float dx = xi - birth;
            float dy = xi - pers;
            s_gxw[slot * STRIDE + i] = pers * __expf(-50.0f * dx * dx);
            s_gy [slot * STRIDE + i] =        __expf(-50.0f * dy * dy);
        }
    }
    __syncthreads();

    // ---- Phase 2: threads 0..199 each own cells (i, j0) and (i, j0+1)
    if (tid < 200) {
        int i  = tid / 10;
        int j0 = (tid % 10) * 2;
        float acc0 = 0.0f, acc1 = 0.0f;
        #pragma unroll 4
        for (int p = 0; p < total; ++p) {
            float  gx = s_gxw[p * STRIDE + i];
            float2 gy = *(const float2*)&s_gy[p * STRIDE + j0];
            acc0 = fmaf(gx, gy.x, acc0);
            acc1 = fmaf(gx, gy.y, acc1);
        }
        float* o = out + (bd * RX + i) * RY + j0;
        atomicAdd(o,     acc0);
        atomicAdd(o + 1, acc1);
    }
}

extern "C" void kernel_launch(void* const* d_in, const int* in_sizes, int n_in,
                              void* d_out, int out_size, void* d_ws, size_t ws_size,
                              hipStream_t stream) {
    const float2* pd = (const float2*)d_in[0];
    float* out = (float*)d_out;
    int n_bd = in_sizes[0] / (2048 * 2);   // 32*3 = 96
    hipMemsetAsync(d_out, 0, (size_t)out_size * sizeof(float), stream);
    pimg_kernel<<<dim3(n_bd * SPLIT), dim3(256), 0, stream>>>(pd, out, n_bd);
}